// Round 1
// 142.742 us; speedup vs baseline: 1.0772x; 1.0772x over previous
//
#include <hip/hip_runtime.h>

// ---------------------------------------------------------------------------
// Gate_16501264351574: conv3x3(256ch -> 64 experts) + sigmoid + top8 + softmax
//   x: [16,256,64,64] f32, gate_w: [64,256,3,3] f32, bias: [64] f32
// out (flat f32): weights [16,8,64,64] | indices-as-f32 [16,8,64,64] | counts[64]
//
// R9: de-entangle the vmcnt streams. R8 issued the HBM staging loads before
// the per-tap B (L2) loads; vmcnt is in-order, so every mfma tap + commit
// inherited HBM latency, phase-aligned across the barrier-locked waves
// (MfmaUtil 8.6%, 75% idle). Now:
//   - staging is a 2-chunk pipeline: chunk q commits (pure ds_write, loads a
//     full chunk old -> no vm wait) data for q+1, issues loads for q+2.
//   - OOB halo zeroed ONCE in prologue; commits are tOk-guarded only.
//   - B fragments lead-3: taps 0-2 loaded before the previous barrier (ride
//     the drain), in-chunk pB(t) issued right after tap(t-3) frees the slot.
//   - staging batch pinned after tap5 via sched_barrier(0) so taps 6-8's B
//     is issued before the HBM batch; no tap waits behind staging.
// Slots stay depth-3 (t%3 static), q-loop stays #pragma unroll 1.
// ---------------------------------------------------------------------------

typedef _Float16 half8 __attribute__((ext_vector_type(8)));
typedef __attribute__((ext_vector_type(4))) float f32x4;

#define LOG2E 1.44269504f

__device__ __forceinline__ unsigned short f2h_bits(float f) {
    _Float16 h = (_Float16)f;                  // v_cvt_f16_f32, RNE
    unsigned short b;
    __builtin_memcpy(&b, &h, 2);
    return b;
}

constexpr int WB_U4 = 8 * 9 * 4 * 64;          // 18432 uint4 = 294912 B

// ---------------------------------------------------------------------------
// Prep: gate_w -> f16 B-fragments, chunk-major:
//   wB_u4[((q*9 + t)*4 + nt)*64 + lane]: e = nt*16+(lane&15), c = q*32+(lane>>4)*8+j
// Also zeroes the counts region of out (replaces a memset dispatch).
// ---------------------------------------------------------------------------
__global__ __launch_bounds__(256) void gate_prep(const float* __restrict__ gw,
                                                 unsigned short* __restrict__ wB,
                                                 float* __restrict__ out) {
    int g = blockIdx.x * 256 + threadIdx.x;
    if (blockIdx.x == 0 && threadIdx.x < 64) out[1048576 + threadIdx.x] = 0.f;
    if (g >= WB_U4) return;
    int lane = g & 63;
    int nt   = (g >> 6) & 3;
    int rest = g >> 8;                          // q*9 + t
    int t = rest % 9, q = rest / 9;
    int e  = nt * 16 + (lane & 15);
    int c0 = q * 32 + (lane >> 4) * 8;
    unsigned short o[8];
#pragma unroll
    for (int j = 0; j < 8; ++j)
        o[j] = f2h_bits(gw[(e * 256 + c0 + j) * 9 + t]);
    uint4 pk;
    pk.x = (unsigned)o[0] | ((unsigned)o[1] << 16);
    pk.y = (unsigned)o[2] | ((unsigned)o[3] << 16);
    pk.z = (unsigned)o[4] | ((unsigned)o[5] << 16);
    pk.w = (unsigned)o[6] | ((unsigned)o[7] << 16);
    ((uint4*)wB)[g] = pk;
}

// ---------------------------------------------------------------------------
// Main. Grid 1024 x 256 thr: b = blk&15 (image -> XCD), r = blk>>4 (row).
// Wave rw: ph = rw>>1 (pos half), eh = rw&1 (expert half); tile 32x32.
// LDS: xs double slab [2][3 rows][66 w'][40 c] f16 = 31680 B (+bias+hist);
// epilogue scf [64][68] f32 (17408 B) aliases xs.
// ---------------------------------------------------------------------------
constexpr int CSTR = 40;                       // shorts per (row,w') site
constexpr int SLAB = 3 * 66 * CSTR;            // 7920 shorts = 15840 B
constexpr int SSTR = 68;                       // fp32 score row stride

__global__ __launch_bounds__(256, 4) void gate_main(
    const float* __restrict__ x, const float* __restrict__ bias,
    const unsigned short* __restrict__ wB, float* __restrict__ out) {
    __shared__ unsigned short xs[2 * SLAB];    // 31680 B
    __shared__ float bias_s[64];
    __shared__ int   hist[64];

    const int tid  = threadIdx.x;
    const int lane = tid & 63;
    const int rw   = tid >> 6;
    const int blk  = blockIdx.x;
    const int b    = blk & 15;
    const int r    = blk >> 4;                 // output row 0..63

    if (tid < 64) { bias_s[tid] = bias[tid]; hist[tid] = 0; }

    // ---- zero both slabs once (halo/OOB sites stay zero forever) ----------
    {
        uint4 z = {0u, 0u, 0u, 0u};
        uint4* p = (uint4*)xs;                 // 2*SLAB/8 = 1980 uint4
#pragma unroll
        for (int i = 0; i < 8; ++i) {
            int idx = tid + i * 256;
            if (idx < 2 * SLAB / 8) p[idx] = z;
        }
    }

    // ---- staging task descriptors (4 tasks/thread, precomputed) ----------
    // Task T = tid + i*256, T < 792 = 198 sites x 4 channel-groups(8ch).
    bool tOk[4];
    int  tSrc[4], tDst[4];
#pragma unroll
    for (int i = 0; i < 4; ++i) {
        int T = tid + i * 256;
        bool ex = (T < 792);
        int chh = T / 198, s = T - chh * 198;
        int row2 = s / 66, wp = s - row2 * 66;
        int gr = r - 1 + row2, gwc = wp - 1;
        tOk[i]  = ex && (gr >= 0) && (gr < 64) && (gwc >= 0) && (gwc < 64);
        tSrc[i] = ((b * 256 + chh * 8) * 64 + gr) * 64 + gwc;   // + dq*131072
        tDst[i] = (row2 * 66 + wp) * CSTR + chh * 8;            // shorts
    }

    // tb: staged f32, held across ONE barrier (issued in q for chunk q+2,
    // committed at top of q+1). 32 VGPRs, statically indexed.
    float tb[4][8];
    auto issueT = [&](int i, int dq) {
        if (tOk[i]) {
            const float* p = x + tSrc[i] + dq * 131072;
#pragma unroll
            for (int u = 0; u < 8; ++u) tb[i][u] = p[u * 4096];
        }
    };
    auto commitT = [&](int i, unsigned short* dst) {
        if (tOk[i]) {
            uint4 pk;
            pk.x = (unsigned)f2h_bits(tb[i][0]) | ((unsigned)f2h_bits(tb[i][1]) << 16);
            pk.y = (unsigned)f2h_bits(tb[i][2]) | ((unsigned)f2h_bits(tb[i][3]) << 16);
            pk.z = (unsigned)f2h_bits(tb[i][4]) | ((unsigned)f2h_bits(tb[i][5]) << 16);
            pk.w = (unsigned)f2h_bits(tb[i][6]) | ((unsigned)f2h_bits(tb[i][7]) << 16);
            *(uint4*)(dst + tDst[i]) = pk;
        }
    };

    // ---- fragment slots (3-deep rotation, statically indexed) -------------
    const int ph = rw >> 1, eh = rw & 1;
    half8 Aa[3][2];
    uint4 Bb[3][2];
    auto prefA = [&](const unsigned short* buf, int t, int slot) {
        const int kh = t / 3, kw = t % 3;
        const unsigned short* abase =
            buf + (kh * 66 + ph * 32 + (lane & 15) + kw) * CSTR + (lane >> 4) * 8;
#pragma unroll
        for (int mt = 0; mt < 2; ++mt)
            Aa[slot][mt] = *(const half8*)(abase + mt * 16 * CSTR);
    };
    auto prefB = [&](int T9, int slot) {       // T9 = q*9 + t, global tap id
        const uint4* bp = (const uint4*)wB + (T9 * 4 + eh * 2) * 64 + lane;
#pragma unroll
        for (int nt = 0; nt < 2; ++nt) Bb[slot][nt] = bp[nt * 64];
    };

    f32x4 acc[2][2];
#pragma unroll
    for (int mt = 0; mt < 2; ++mt)
#pragma unroll
        for (int nt = 0; nt < 2; ++nt) acc[mt][nt] = (f32x4){0.f, 0.f, 0.f, 0.f};

    auto mfma_tap = [&](int slot) {
#pragma unroll
        for (int nt = 0; nt < 2; ++nt) {
            half8 bfr;
            __builtin_memcpy(&bfr, &Bb[slot][nt], 16);
#pragma unroll
            for (int mt = 0; mt < 2; ++mt)
                acc[mt][nt] = __builtin_amdgcn_mfma_f32_16x16x32_f16(
                    Aa[slot][mt], bfr, acc[mt][nt], 0, 0, 0);
        }
    };

    // ---- prologue ---------------------------------------------------------
    __syncthreads();                           // zeroed slabs visible

    issueT(0, 0); issueT(1, 0); issueT(2, 0); issueT(3, 0);    // chunk 0
    commitT(0, xs); commitT(1, xs); commitT(2, xs); commitT(3, xs);
    issueT(0, 1); issueT(1, 1); issueT(2, 1); issueT(3, 1);    // pre-stage 1
    prefB(0, 0); prefB(1, 1); prefB(2, 2);     // chunk-0 taps 0..2 B frags
    __syncthreads();

    // ---- K loop: 8 chunks x 9 taps, 1 barrier per chunk -------------------
#pragma unroll 1
    for (int q = 0; q < 8; ++q) {
        const unsigned short* cur = xs + (q & 1) * SLAB;
        unsigned short*       nxt = xs + ((q + 1) & 1) * SLAB;
        const int  T0  = q * 9;
        const bool cmt = (q < 7);
        const bool iss = (q < 6);

        prefA(cur, 0, 0); prefA(cur, 1, 1);
        // commit pre-staged chunk q+1 (loads a full chunk old -> no vm wait)
        if (cmt) { commitT(0, nxt); commitT(1, nxt); commitT(2, nxt); commitT(3, nxt); }
        mfma_tap(0); prefB(T0 + 3, 0); prefA(cur, 2, 2);
        mfma_tap(1); prefB(T0 + 4, 1); prefA(cur, 3, 0);
        mfma_tap(2); prefB(T0 + 5, 2); prefA(cur, 4, 1);
        mfma_tap(0); prefB(T0 + 6, 0); prefA(cur, 5, 2);
        mfma_tap(1); prefB(T0 + 7, 1); prefA(cur, 6, 0);
        mfma_tap(2); prefB(T0 + 8, 2); prefA(cur, 7, 1);
        // HBM staging batch for chunk q+2, pinned here so taps 6-8's B frags
        // (issued above) are OLDER than it in the vmcnt queue.
        __builtin_amdgcn_sched_barrier(0);
        if (iss) { issueT(0, q + 2); issueT(1, q + 2); issueT(2, q + 2); issueT(3, q + 2); }
        __builtin_amdgcn_sched_barrier(0);
        mfma_tap(0); if (cmt) prefB(T0 + 9, 0);  prefA(cur, 8, 2);
        mfma_tap(1); if (cmt) prefB(T0 + 10, 1);
        mfma_tap(2); if (cmt) prefB(T0 + 11, 2); // next-chunk taps 0..2
        __syncthreads();
    }

    // ---- epilogue: sigmoid -> fp32 scores in LDS (aliases xs) -------------
    float* scf = (float*)xs;                   // [64][68] f32 = 17408 B
#pragma unroll
    for (int mt = 0; mt < 2; ++mt)
#pragma unroll
        for (int nt = 0; nt < 2; ++nt)
#pragma unroll
            for (int rr = 0; rr < 4; ++rr) {
                float v = acc[mt][nt][rr];
                float s = 1.f / (1.f + __builtin_amdgcn_exp2f(-v * LOG2E));
                int p = ph * 32 + mt * 16 + ((lane >> 4) << 2) + rr;
                int e = eh * 32 + nt * 16 + (lane & 15);
                scf[p * SSTR + e] = s;
            }
    __syncthreads();

    if (tid < 64) {
        // top-8 of 64; jax tie-break (lower idx first): ascending scan + strict >
        const float* row = scf + tid * SSTR;
        float tv[8];
        int   ti[8];
#pragma unroll
        for (int k = 0; k < 8; ++k) { tv[k] = -3.0e38f; ti[k] = 0; }
#pragma unroll
        for (int j4 = 0; j4 < 16; ++j4) {
            f32x4 blkv = *(const f32x4*)(row + j4 * 4);
#pragma unroll
            for (int j = 0; j < 4; ++j) {
                int   e  = j4 * 4 + j;
                float bs = blkv[j] + bias_s[e];
                if (bs > tv[7]) {
                    tv[7] = bs; ti[7] = e;
#pragma unroll
                    for (int k = 7; k > 0; --k) {
                        float fa = tv[k - 1], fb = tv[k];
                        int   ia = ti[k - 1], ib = ti[k];
                        bool  sw = fb > fa;
                        tv[k - 1] = sw ? fb : fa; tv[k] = sw ? fa : fb;
                        ti[k - 1] = sw ? ib : ia; ti[k] = sw ? ia : ib;
                    }
                }
            }
        }
        // softmax over UNbiased scores of the selected 8
        float u[8], mx = -3.0e38f;
#pragma unroll
        for (int k = 0; k < 8; ++k) { u[k] = tv[k] - bias_s[ti[k]]; mx = fmaxf(mx, u[k]); }
        float ex[8], sum = 0.f;
#pragma unroll
        for (int k = 0; k < 8; ++k) { ex[k] = __builtin_amdgcn_exp2f((u[k] - mx) * LOG2E); sum += ex[k]; }
        float inv = 1.f / sum;

        int obase = b * 32768 + r * 64 + tid;  // [b][k][h=r][w=tid]
#pragma unroll
        for (int k = 0; k < 8; ++k) {
            out[obase + k * 4096]          = ex[k] * inv;     // weights
            out[524288 + obase + k * 4096] = (float)ti[k];    // indices (as f32)
            atomicAdd(&hist[ti[k]], 1);
        }
    }
    __syncthreads();
    if (tid < 64) atomicAdd(out + 1048576 + tid, (float)hist[tid]);  // counts
}

// ---------------------------------------------------------------------------
extern "C" void kernel_launch(void* const* d_in, const int* in_sizes, int n_in,
                              void* d_out, int out_size, void* d_ws, size_t ws_size,
                              hipStream_t stream) {
    const float* x    = (const float*)d_in[0];
    const float* gw   = (const float*)d_in[1];
    const float* bias = (const float*)d_in[2];
    float* out = (float*)d_out;
    unsigned short* wB = (unsigned short*)d_ws;   // 294912 B

    gate_prep<<<72, 256, 0, stream>>>(gw, wB, out);   // also zeroes counts
    gate_main<<<1024, 256, 0, stream>>>(x, bias, wB, out);
}